// Round 1
// baseline (759.803 us; speedup 1.0000x reference)
//
#include <hip/hip_runtime.h>

#define B_ 8
#define T_ 1024
#define D_ 256
#define NBAND 7
#define MROWS (B_*T_)             // 8192 rows per band
#define BAND_ELEMS (MROWS*D_)     // 2097152

typedef __attribute__((ext_vector_type(8))) short bf16x8;
typedef __attribute__((ext_vector_type(4))) float f32x4;

__device__ __forceinline__ unsigned short f2bf(float f) {
  unsigned int u = __float_as_uint(f);
  u = u + 0x7fffu + ((u >> 16) & 1u);
  return (unsigned short)(u >> 16);
}
__device__ __forceinline__ float bf2f(unsigned short h) {
  return __uint_as_float(((unsigned int)h) << 16);
}

// ---------------- conversion fp32 -> bf16 ----------------
struct CvtSeg { const float* src; unsigned short* dst; int n; };
struct CvtParams { CvtSeg seg[14]; };

__global__ __launch_bounds__(256) void cvt_kernel(CvtParams p) {
  CvtSeg s = p.seg[blockIdx.y];
  int i = (blockIdx.x * 256 + threadIdx.x) * 4;
  if (i >= s.n) return;
  float4 v = *(const float4*)(s.src + i);
  ushort4 o;
  o.x = f2bf(v.x); o.y = f2bf(v.y); o.z = f2bf(v.z); o.w = f2bf(v.w);
  *(ushort4*)(s.dst + i) = o;
}

// ---------------- GEMM core: wave computes 16 rows x 64 cols ----------------
// A row-major [M,256] bf16 (A1 supplies k>=256 when KTOT=512), W row-major [N,KTOT] bf16.
template<int KTOT>
__device__ __forceinline__ void gemm_strip(const unsigned short* __restrict__ A0,
                                           const unsigned short* __restrict__ A1,
                                           const unsigned short* __restrict__ W,
                                           int m0, f32x4 acc[4]) {
  const int lane = threadIdx.x & 63;
  const int wv   = threadIdx.x >> 6;
  const int quad = lane >> 4;
  const int l15  = lane & 15;
  const unsigned short* ar0 = A0 + (m0 + l15) * 256 + quad * 8;
  const unsigned short* ar1 = (KTOT == 512) ? (A1 + (m0 + l15) * 256 + quad * 8) : A0;
  const unsigned short* wr  = W + (wv * 64 + l15) * KTOT + quad * 8;
#pragma unroll
  for (int kc = 0; kc < KTOT / 32; ++kc) {
    bf16x8 a;
    if (KTOT == 512 && kc >= 8) a = *(const bf16x8*)(ar1 + kc * 32 - 256);
    else                        a = *(const bf16x8*)(ar0 + kc * 32);
#pragma unroll
    for (int j = 0; j < 4; ++j) {
      bf16x8 b = *(const bf16x8*)(wr + j * 16 * KTOT + kc * 32);
      acc[j] = __builtin_amdgcn_mfma_f32_16x16x32_bf16(a, b, acc[j], 0, 0, 0);
    }
  }
}

// ---------------- Q/K/V projection ----------------
struct ProjParams {
  const unsigned short* bands;   // [7][8192][256]
  const unsigned short* w[3];    // each [7][256][256]
  const float* bias[3];          // each [7][256] fp32
  unsigned short* dst[3];        // q,k,v [7][8192][256]
};
__global__ __launch_bounds__(256) void proj_kernel(ProjParams p) {
  const int z = blockIdx.z;
  const int n = z / 3, which = z % 3;
  const unsigned short* A = p.bands + n * BAND_ELEMS;
  const unsigned short* W = p.w[which] + n * D_ * D_;
  const float* bias = p.bias[which] + n * D_;
  unsigned short* Dst = p.dst[which] + n * BAND_ELEMS;
  const int m0 = blockIdx.x * 16;
  f32x4 acc[4];
#pragma unroll
  for (int j = 0; j < 4; ++j) acc[j] = (f32x4){0.f, 0.f, 0.f, 0.f};
  gemm_strip<256>(A, A, W, m0, acc);
  const int lane = threadIdx.x & 63, wv = threadIdx.x >> 6;
  const int quad = lane >> 4, l15 = lane & 15;
#pragma unroll
  for (int j = 0; j < 4; ++j) {
    int col = wv * 64 + j * 16 + l15;
    float bc = bias[col];
#pragma unroll
    for (int r = 0; r < 4; ++r) {
      int rm = m0 + quad * 4 + r;
      Dst[rm * D_ + col] = f2bf(acc[j][r] + bc);
    }
  }
}

// ---------------- windowed causal attention: one wave per query row ----------------
__global__ __launch_bounds__(256) void attn_kernel(const unsigned short* __restrict__ q,
                                                   const unsigned short* __restrict__ k,
                                                   const unsigned short* __restrict__ v,
                                                   unsigned short* __restrict__ ctx) {
  __shared__ float smem[4][128];
  const int wv = threadIdx.x >> 6, lane = threadIdx.x & 63;
  const int wid = blockIdx.x * 4 + wv;          // 0..57343
  const int n = wid >> 13;
  const int rem = wid & 8191;
  const int b = rem >> 10;
  const int t = rem & 1023;
  const int w = 1 << ((0x2344567u >> (4 * n)) & 0xFu);
  int jlo = t - w + 1; if (jlo < 0) jlo = 0;
  const int cnt = t - jlo + 1;
  const int base = ((n * B_ + b) * T_) * D_;
  const int d0 = lane * 4;
  ushort4 qr = *(const ushort4*)(q + base + t * D_ + d0);
  const float q0 = bf2f(qr.x), q1 = bf2f(qr.y), q2 = bf2f(qr.z), q3 = bf2f(qr.w);
  float* sc = smem[wv];
  float mx = -1e30f;
  for (int jj = 0; jj < cnt; ++jj) {
    ushort4 kr = *(const ushort4*)(k + base + (jlo + jj) * D_ + d0);
    float pp = q0 * bf2f(kr.x) + q1 * bf2f(kr.y) + q2 * bf2f(kr.z) + q3 * bf2f(kr.w);
#pragma unroll
    for (int off = 32; off; off >>= 1) pp += __shfl_xor(pp, off, 64);
    pp *= 0.0625f;                              // 1/sqrt(256)
    if (lane == 0) sc[jj] = pp;
    mx = fmaxf(mx, pp);
  }
  float ssum = 0.f;
  for (int jj = lane; jj < cnt; jj += 64) {
    float e = __expf(sc[jj] - mx);
    sc[jj] = e;
    ssum += e;
  }
#pragma unroll
  for (int off = 32; off; off >>= 1) ssum += __shfl_xor(ssum, off, 64);
  const float inv = 1.f / ssum;
  float a0 = 0.f, a1 = 0.f, a2 = 0.f, a3 = 0.f;
  for (int jj = 0; jj < cnt; ++jj) {
    float pp = sc[jj];
    ushort4 vr = *(const ushort4*)(v + base + (jlo + jj) * D_ + d0);
    a0 += pp * bf2f(vr.x); a1 += pp * bf2f(vr.y);
    a2 += pp * bf2f(vr.z); a3 += pp * bf2f(vr.w);
  }
  ushort4 o;
  o.x = f2bf(a0 * inv); o.y = f2bf(a1 * inv);
  o.z = f2bf(a2 * inv); o.w = f2bf(a3 * inv);
  *(ushort4*)(ctx + base + t * D_ + d0) = o;
}

// ---------------- other = (sum_n ctx - ctx[3]) / 6 ----------------
__global__ __launch_bounds__(256) void other_kernel(const unsigned short* __restrict__ ctx,
                                                    unsigned short* __restrict__ other) {
  int i = (blockIdx.x * 256 + threadIdx.x) * 4;
  if (i >= BAND_ELEMS) return;
  float s0 = 0.f, s1 = 0.f, s2 = 0.f, s3 = 0.f;
#pragma unroll
  for (int nn = 0; nn < 7; ++nn) {
    if (nn == 3) continue;
    ushort4 c = *(const ushort4*)(ctx + nn * BAND_ELEMS + i);
    s0 += bf2f(c.x); s1 += bf2f(c.y); s2 += bf2f(c.z); s3 += bf2f(c.w);
  }
  const float inv6 = 1.f / 6.f;
  ushort4 o;
  o.x = f2bf(s0 * inv6); o.y = f2bf(s1 * inv6);
  o.z = f2bf(s2 * inv6); o.w = f2bf(s3 * inv6);
  *(ushort4*)(other + i) = o;
}

// ---------------- inject projections (cross / crossr / bridge) ----------------
struct InjParams {
  const unsigned short* src[7];
  const unsigned short* w[7];
  const float* bias[7];
  unsigned short* inject;
};
__global__ __launch_bounds__(256) void inject_kernel(InjParams p) {
  const int i = blockIdx.z;
  const unsigned short* A = p.src[i];
  const unsigned short* W = p.w[i];
  const float* bias = p.bias[i];
  unsigned short* Dst = p.inject + i * BAND_ELEMS;
  const int m0 = blockIdx.x * 16;
  f32x4 acc[4];
#pragma unroll
  for (int j = 0; j < 4; ++j) acc[j] = (f32x4){0.f, 0.f, 0.f, 0.f};
  gemm_strip<256>(A, A, W, m0, acc);
  const int lane = threadIdx.x & 63, wv = threadIdx.x >> 6;
  const int quad = lane >> 4, l15 = lane & 15;
#pragma unroll
  for (int j = 0; j < 4; ++j) {
    int col = wv * 64 + j * 16 + l15;
    float bc = bias[col];
#pragma unroll
    for (int r = 0; r < 4; ++r) {
      int rm = m0 + quad * 4 + r;
      Dst[rm * D_ + col] = f2bf(acc[j][r] + bc);
    }
  }
}

// ---------------- gate + output ----------------
struct GateParams {
  const unsigned short* bands;   // bf16 [7][8192][256]
  const unsigned short* inject;  // bf16 [7][8192][256]
  const unsigned short* gatew;   // bf16 [7][256][512]
  const float* gateb;            // fp32 [7][256]
  const float* bandf[7];         // original fp32 bands
  float* out;                    // [7][8192][256]
};
__global__ __launch_bounds__(256) void gate_kernel(GateParams p) {
  const int i = blockIdx.z;
  const unsigned short* A0 = p.bands + i * BAND_ELEMS;
  const unsigned short* A1 = p.inject + i * BAND_ELEMS;
  const unsigned short* W = p.gatew + i * D_ * 512;
  const float* bias = p.gateb + i * D_;
  const float* bf = p.bandf[i];
  float* out = p.out + i * BAND_ELEMS;
  const int m0 = blockIdx.x * 16;
  f32x4 acc[4];
#pragma unroll
  for (int j = 0; j < 4; ++j) acc[j] = (f32x4){0.f, 0.f, 0.f, 0.f};
  gemm_strip<512>(A0, A1, W, m0, acc);
  const int lane = threadIdx.x & 63, wv = threadIdx.x >> 6;
  const int quad = lane >> 4, l15 = lane & 15;
#pragma unroll
  for (int j = 0; j < 4; ++j) {
    int col = wv * 64 + j * 16 + l15;
    float bc = bias[col];
#pragma unroll
    for (int r = 0; r < 4; ++r) {
      int rm = m0 + quad * 4 + r;
      float g = 1.f / (1.f + __expf(-(acc[j][r] + bc)));
      float inj = bf2f(A1[rm * D_ + col]);
      out[rm * D_ + col] = bf[rm * D_ + col] + g * inj;
    }
  }
}

// ---------------- host launch ----------------
extern "C" void kernel_launch(void* const* d_in, const int* in_sizes, int n_in,
                              void* d_out, int out_size, void* d_ws, size_t ws_size,
                              hipStream_t stream) {
  const float* band[7];
  for (int i = 0; i < 7; ++i) band[i] = (const float*)d_in[i];
  const float* qw = (const float*)d_in[7];   const float* qb = (const float*)d_in[8];
  const float* kw = (const float*)d_in[9];   const float* kb = (const float*)d_in[10];
  const float* vw = (const float*)d_in[11];  const float* vb = (const float*)d_in[12];
  const float* crossw  = (const float*)d_in[13]; const float* crossb  = (const float*)d_in[14];
  const float* crossrw = (const float*)d_in[15]; const float* crossrb = (const float*)d_in[16];
  const float* gatew = (const float*)d_in[17];   const float* gateb = (const float*)d_in[18];
  const float* bridgew = (const float*)d_in[19]; const float* bridgeb = (const float*)d_in[20];

  // workspace layout (bf16 = unsigned short elements)
  unsigned short* ws = (unsigned short*)d_ws;
  unsigned short* bands_bf = ws;
  unsigned short* qbf      = bands_bf + 7 * BAND_ELEMS;
  unsigned short* kbf      = qbf + 7 * BAND_ELEMS;
  unsigned short* vbf      = kbf + 7 * BAND_ELEMS;
  unsigned short* ctx      = vbf + 7 * BAND_ELEMS;
  unsigned short* inject   = ctx + 7 * BAND_ELEMS;
  unsigned short* other    = inject + 7 * BAND_ELEMS;
  unsigned short* qw_bf    = other + BAND_ELEMS;
  unsigned short* kw_bf    = qw_bf + 7 * 65536;
  unsigned short* vw_bf    = kw_bf + 7 * 65536;
  unsigned short* crossw_bf  = vw_bf + 7 * 65536;
  unsigned short* crossrw_bf = crossw_bf + 3 * 65536;
  unsigned short* gatew_bf   = crossrw_bf + 3 * 65536;
  unsigned short* bridgew_bf = gatew_bf + 7 * 131072;
  const size_t needed = (size_t)(6 * 7 * BAND_ELEMS + BAND_ELEMS +
                                 3 * 7 * 65536 + 2 * 3 * 65536 + 7 * 131072 + 65536) * 2;
  if (ws_size < needed) return;  // fail visibly (poisoned output) rather than corrupt

  CvtParams cp;
  for (int i = 0; i < 7; ++i) cp.seg[i] = {band[i], bands_bf + i * BAND_ELEMS, BAND_ELEMS};
  cp.seg[7]  = {qw, qw_bf, 7 * 65536};
  cp.seg[8]  = {kw, kw_bf, 7 * 65536};
  cp.seg[9]  = {vw, vw_bf, 7 * 65536};
  cp.seg[10] = {crossw, crossw_bf, 3 * 65536};
  cp.seg[11] = {crossrw, crossrw_bf, 3 * 65536};
  cp.seg[12] = {gatew, gatew_bf, 7 * 131072};
  cp.seg[13] = {bridgew, bridgew_bf, 65536};
  cvt_kernel<<<dim3(BAND_ELEMS / 1024, 14), 256, 0, stream>>>(cp);

  ProjParams pp;
  pp.bands = bands_bf;
  pp.w[0] = qw_bf; pp.w[1] = kw_bf; pp.w[2] = vw_bf;
  pp.bias[0] = qb; pp.bias[1] = kb; pp.bias[2] = vb;
  pp.dst[0] = qbf; pp.dst[1] = kbf; pp.dst[2] = vbf;
  proj_kernel<<<dim3(MROWS / 16, 1, 21), 256, 0, stream>>>(pp);

  attn_kernel<<<dim3((NBAND * MROWS) / 4), 256, 0, stream>>>(qbf, kbf, vbf, ctx);

  other_kernel<<<dim3(BAND_ELEMS / 1024), 256, 0, stream>>>(ctx, other);

  InjParams ip;
  // pairs: (low,high) = (0,6),(1,5),(2,4)
  ip.src[6] = ctx + 0 * BAND_ELEMS; ip.w[6] = crossw_bf + 0 * 65536; ip.bias[6] = crossb + 0 * 256;
  ip.src[5] = ctx + 1 * BAND_ELEMS; ip.w[5] = crossw_bf + 1 * 65536; ip.bias[5] = crossb + 1 * 256;
  ip.src[4] = ctx + 2 * BAND_ELEMS; ip.w[4] = crossw_bf + 2 * 65536; ip.bias[4] = crossb + 2 * 256;
  ip.src[0] = ctx + 6 * BAND_ELEMS; ip.w[0] = crossrw_bf + 0 * 65536; ip.bias[0] = crossrb + 0 * 256;
  ip.src[1] = ctx + 5 * BAND_ELEMS; ip.w[1] = crossrw_bf + 1 * 65536; ip.bias[1] = crossrb + 1 * 256;
  ip.src[2] = ctx + 4 * BAND_ELEMS; ip.w[2] = crossrw_bf + 2 * 65536; ip.bias[2] = crossrb + 2 * 256;
  ip.src[3] = other;                ip.w[3] = bridgew_bf;             ip.bias[3] = bridgeb;
  ip.inject = inject;
  inject_kernel<<<dim3(MROWS / 16, 1, 7), 256, 0, stream>>>(ip);

  GateParams gp;
  gp.bands = bands_bf; gp.inject = inject;
  gp.gatew = gatew_bf; gp.gateb = gateb;
  for (int i = 0; i < 7; ++i) gp.bandf[i] = band[i];
  gp.out = (float*)d_out;
  gate_kernel<<<dim3(MROWS / 16, 1, 7), 256, 0, stream>>>(gp);
}

// Round 2
// 592.777 us; speedup vs baseline: 1.2818x; 1.2818x over previous
//
#include <hip/hip_runtime.h>

#define B_ 8
#define T_ 1024
#define D_ 256
#define NBAND 7
#define MROWS (B_*T_)             // 8192 rows per band
#define BAND_ELEMS (MROWS*D_)     // 2097152

typedef __attribute__((ext_vector_type(8))) short bf16x8;
typedef __attribute__((ext_vector_type(4))) float f32x4;
typedef unsigned short ushort_t;

__device__ __forceinline__ unsigned short f2bf(float f) {
  unsigned int u = __float_as_uint(f);
  u = u + 0x7fffu + ((u >> 16) & 1u);
  return (unsigned short)(u >> 16);
}
__device__ __forceinline__ float bf2f(unsigned short h) {
  return __uint_as_float(((unsigned int)h) << 16);
}

// ---------------- conversion fp32 -> bf16 ----------------
struct CvtSeg { const float* src; unsigned short* dst; int n; };
struct CvtParams { CvtSeg seg[14]; };

__global__ __launch_bounds__(256) void cvt_kernel(CvtParams p) {
  CvtSeg s = p.seg[blockIdx.y];
  int i = (blockIdx.x * 256 + threadIdx.x) * 4;
  if (i >= s.n) return;
  float4 v = *(const float4*)(s.src + i);
  ushort4 o;
  o.x = f2bf(v.x); o.y = f2bf(v.y); o.z = f2bf(v.z); o.w = f2bf(v.w);
  *(ushort4*)(s.dst + i) = o;
}

// ================= GEMM: register-resident W, 32 row-tiles per block =======
// Wave holds W strip (COLS cols x K) in 16 bf16x8 frags (64 VGPRs), loops row
// tiles. K=256: COLS=32 (2 j-frags x 8 kc). Block = 4 waves = 128 cols.

// ---------------- Q/K/V projection: z = n*3+which ----------------
struct ProjParams {
  const unsigned short* bands;   // [7][8192][256]
  const unsigned short* w[3];    // each [7][256][256]
  const float* bias[3];          // each [7][256] fp32
  unsigned short* dst[3];        // q,k,v [7][8192][256]
};
__global__ __launch_bounds__(256) void proj_kernel(ProjParams p) {
  const int z = blockIdx.z;
  const int n = z / 3, which = z % 3;
  const unsigned short* A = p.bands + n * BAND_ELEMS;
  const unsigned short* W = p.w[which] + n * D_ * D_;
  const float* bias = p.bias[which] + n * D_;
  unsigned short* Dst = p.dst[which] + n * BAND_ELEMS;

  const int lane = threadIdx.x & 63, wv = threadIdx.x >> 6;
  const int quad = lane >> 4, l15 = lane & 15;
  const int col0 = (blockIdx.y * 4 + wv) * 32;

  bf16x8 wf[8][2];
  {
    const unsigned short* wr = W + (col0 + l15) * 256 + quad * 8;
#pragma unroll
    for (int kc = 0; kc < 8; ++kc)
#pragma unroll
      for (int j = 0; j < 2; ++j)
        wf[kc][j] = *(const bf16x8*)(wr + j * 16 * 256 + kc * 32);
  }
  const float b0 = bias[col0 + l15];
  const float b1 = bias[col0 + 16 + l15];

  for (int tile = 0; tile < 32; ++tile) {
    const int m0 = blockIdx.x * 512 + tile * 16;
    const unsigned short* ar = A + (m0 + l15) * 256 + quad * 8;
    bf16x8 af[8];
#pragma unroll
    for (int kc = 0; kc < 8; ++kc) af[kc] = *(const bf16x8*)(ar + kc * 32);
    f32x4 acc0 = (f32x4){0.f,0.f,0.f,0.f}, acc1 = (f32x4){0.f,0.f,0.f,0.f};
#pragma unroll
    for (int kc = 0; kc < 8; ++kc) {
      acc0 = __builtin_amdgcn_mfma_f32_16x16x32_bf16(af[kc], wf[kc][0], acc0, 0, 0, 0);
      acc1 = __builtin_amdgcn_mfma_f32_16x16x32_bf16(af[kc], wf[kc][1], acc1, 0, 0, 0);
    }
#pragma unroll
    for (int r = 0; r < 4; ++r) {
      int rm = m0 + quad * 4 + r;
      Dst[rm * D_ + col0 + l15]      = f2bf(acc0[r] + b0);
      Dst[rm * D_ + col0 + 16 + l15] = f2bf(acc1[r] + b1);
    }
  }
}

// ---------------- inject projections (cross / crossr / bridge), z = band ----
struct InjParams {
  const unsigned short* src[7];
  const unsigned short* w[7];
  const float* bias[7];
  unsigned short* inject;
};
__global__ __launch_bounds__(256) void inject_kernel(InjParams p) {
  const int i = blockIdx.z;
  const unsigned short* A = p.src[i];
  const unsigned short* W = p.w[i];
  const float* bias = p.bias[i];
  unsigned short* Dst = p.inject + i * BAND_ELEMS;

  const int lane = threadIdx.x & 63, wv = threadIdx.x >> 6;
  const int quad = lane >> 4, l15 = lane & 15;
  const int col0 = (blockIdx.y * 4 + wv) * 32;

  bf16x8 wf[8][2];
  {
    const unsigned short* wr = W + (col0 + l15) * 256 + quad * 8;
#pragma unroll
    for (int kc = 0; kc < 8; ++kc)
#pragma unroll
      for (int j = 0; j < 2; ++j)
        wf[kc][j] = *(const bf16x8*)(wr + j * 16 * 256 + kc * 32);
  }
  const float b0 = bias[col0 + l15];
  const float b1 = bias[col0 + 16 + l15];

  for (int tile = 0; tile < 32; ++tile) {
    const int m0 = blockIdx.x * 512 + tile * 16;
    const unsigned short* ar = A + (m0 + l15) * 256 + quad * 8;
    bf16x8 af[8];
#pragma unroll
    for (int kc = 0; kc < 8; ++kc) af[kc] = *(const bf16x8*)(ar + kc * 32);
    f32x4 acc0 = (f32x4){0.f,0.f,0.f,0.f}, acc1 = (f32x4){0.f,0.f,0.f,0.f};
#pragma unroll
    for (int kc = 0; kc < 8; ++kc) {
      acc0 = __builtin_amdgcn_mfma_f32_16x16x32_bf16(af[kc], wf[kc][0], acc0, 0, 0, 0);
      acc1 = __builtin_amdgcn_mfma_f32_16x16x32_bf16(af[kc], wf[kc][1], acc1, 0, 0, 0);
    }
#pragma unroll
    for (int r = 0; r < 4; ++r) {
      int rm = m0 + quad * 4 + r;
      Dst[rm * D_ + col0 + l15]      = f2bf(acc0[r] + b0);
      Dst[rm * D_ + col0 + 16 + l15] = f2bf(acc1[r] + b1);
    }
  }
}

// ---------------- gate + output: K=512 (band | inject), COLS=16/wave --------
struct GateParams {
  const unsigned short* bands;   // bf16 [7][8192][256]
  const unsigned short* inject;  // bf16 [7][8192][256]
  const unsigned short* gatew;   // bf16 [7][256][512]
  const float* gateb;            // fp32 [7][256]
  const float* bandf[7];         // original fp32 bands
  float* out;                    // [7][8192][256]
};
__global__ __launch_bounds__(256) void gate_kernel(GateParams p) {
  const int i = blockIdx.z;
  const unsigned short* A0 = p.bands + i * BAND_ELEMS;
  const unsigned short* A1 = p.inject + i * BAND_ELEMS;
  const unsigned short* W = p.gatew + i * D_ * 512;
  const float* bias = p.gateb + i * D_;
  const float* bf = p.bandf[i];
  float* out = p.out + i * BAND_ELEMS;

  const int lane = threadIdx.x & 63, wv = threadIdx.x >> 6;
  const int quad = lane >> 4, l15 = lane & 15;
  const int col0 = (blockIdx.y * 4 + wv) * 16;
  const int col = col0 + l15;

  bf16x8 wf[16];
  {
    const unsigned short* wr = W + col * 512 + quad * 8;
#pragma unroll
    for (int kc = 0; kc < 16; ++kc) wf[kc] = *(const bf16x8*)(wr + kc * 32);
  }
  const float bc = bias[col];

  for (int tile = 0; tile < 32; ++tile) {
    const int m0 = blockIdx.x * 512 + tile * 16;
    f32x4 acc = (f32x4){0.f,0.f,0.f,0.f};
    {
      const unsigned short* ar = A0 + (m0 + l15) * 256 + quad * 8;
      bf16x8 af[8];
#pragma unroll
      for (int kc = 0; kc < 8; ++kc) af[kc] = *(const bf16x8*)(ar + kc * 32);
#pragma unroll
      for (int kc = 0; kc < 8; ++kc)
        acc = __builtin_amdgcn_mfma_f32_16x16x32_bf16(af[kc], wf[kc], acc, 0, 0, 0);
    }
    {
      const unsigned short* ar = A1 + (m0 + l15) * 256 + quad * 8;
      bf16x8 af[8];
#pragma unroll
      for (int kc = 0; kc < 8; ++kc) af[kc] = *(const bf16x8*)(ar + kc * 32);
#pragma unroll
      for (int kc = 0; kc < 8; ++kc)
        acc = __builtin_amdgcn_mfma_f32_16x16x32_bf16(af[kc], wf[kc + 8], acc, 0, 0, 0);
    }
#pragma unroll
    for (int r = 0; r < 4; ++r) {
      int rm = m0 + quad * 4 + r;
      float g = 1.f / (1.f + __expf(-(acc[r] + bc)));
      float inj = bf2f(A1[rm * D_ + col]);
      out[rm * D_ + col] = bf[rm * D_ + col] + g * inj;
    }
  }
}

// ============== attention: MFMA scores + softmax + scalar PV ===============
// Block = 4 waves; each wave owns a 16-row Q tile. Scores via 16x16x32 MFMA
// over <=9 key tiles; softmax on C-layout regs; normalized P staged in LDS;
// PV as broadcast-P scalar loop (V rows coalesced 512B/wave).
__global__ __launch_bounds__(256) void attn_kernel(const unsigned short* __restrict__ q,
                                                   const unsigned short* __restrict__ k,
                                                   const unsigned short* __restrict__ v,
                                                   unsigned short* __restrict__ ctx) {
  __shared__ float plds[4][16][148];   // per-wave P, stride 148 (148%32=20: rows shift banks)
  const int wv = threadIdx.x >> 6, lane = threadIdx.x & 63;
  const int quad = lane >> 4, l15 = lane & 15;
  const int bid = blockIdx.x;              // 7*8*16 = 896
  const int n = bid >> 7;
  const int b = (bid >> 4) & 7;
  const int qblk = bid & 15;
  const int t0 = qblk * 64 + wv * 16;
  const int w = 1 << ((0x2344567u >> (4 * n)) & 0xFu);
  const int base = ((n * B_ + b) * T_) * D_;

  int klo_key = t0 - w + 1; if (klo_key < 0) klo_key = 0;
  const int kt_lo = klo_key >> 4;
  const int kt_hi = t0 >> 4;
  const int ntiles = kt_hi - kt_lo + 1;    // <= 9

  // Q fragments (A layout: m=l15, k=quad*8+j within each 32-chunk)
  bf16x8 qf[8];
  {
    const unsigned short* qr = q + base + (t0 + l15) * D_ + quad * 8;
#pragma unroll
    for (int kc = 0; kc < 8; ++kc) qf[kc] = *(const bf16x8*)(qr + kc * 32);
  }

  // scores: s[it] C layout (col=l15 -> key, row=quad*4+r -> query)
  f32x4 s[9];
#pragma unroll
  for (int it = 0; it < 9; ++it) {
    if (it < ntiles) {
      const int kt = kt_lo + it;
      const unsigned short* kr = k + base + (kt * 16 + l15) * D_ + quad * 8;
      f32x4 acc = (f32x4){0.f,0.f,0.f,0.f};
#pragma unroll
      for (int kc = 0; kc < 8; ++kc) {
        bf16x8 kf = *(const bf16x8*)(kr + kc * 32);
        acc = __builtin_amdgcn_mfma_f32_16x16x32_bf16(qf[kc], kf, acc, 0, 0, 0);
      }
      s[it] = acc;
    }
  }

  // mask + softmax per C-row; write normalized P to LDS
#pragma unroll
  for (int r = 0; r < 4; ++r) {
    const int i = t0 + quad * 4 + r;
    float m = -1e30f;
#pragma unroll
    for (int it = 0; it < 9; ++it) {
      if (it < ntiles) {
        const int j = (kt_lo + it) * 16 + l15;
        float val = s[it][r] * 0.0625f;              // 1/sqrt(256)
        val = (j <= i && j > i - w) ? val : -1e30f;
        s[it][r] = val;
        m = fmaxf(m, val);
      }
    }
#pragma unroll
    for (int off = 8; off; off >>= 1) m = fmaxf(m, __shfl_xor(m, off, 64));
    float l = 0.f;
#pragma unroll
    for (int it = 0; it < 9; ++it) {
      if (it < ntiles) {
        float e = __expf(s[it][r] - m);
        s[it][r] = e;
        l += e;
      }
    }
#pragma unroll
    for (int off = 8; off; off >>= 1) l += __shfl_xor(l, off, 64);
    const float inv = 1.f / l;
#pragma unroll
    for (int it = 0; it < 9; ++it)
      if (it < ntiles)
        plds[wv][quad * 4 + r][it * 16 + l15] = s[it][r] * inv;
  }
  __syncthreads();

  // PV: per q row, stream V rows (coalesced 512B/wave), P broadcast from LDS
  const int d0 = lane * 4;
  const int cbase = kt_lo * 16;
  for (int r16 = 0; r16 < 16; ++r16) {
    const int t = t0 + r16;
    int jlo = t - w + 1; if (jlo < 0) jlo = 0;
    float a0 = 0.f, a1 = 0.f, a2 = 0.f, a3 = 0.f;
    const float* prow = plds[wv][r16];
#pragma unroll 4
    for (int j = jlo; j <= t; ++j) {
      const float p = prow[j - cbase];
      ushort4 vr = *(const ushort4*)(v + base + j * D_ + d0);
      a0 += p * bf2f(vr.x); a1 += p * bf2f(vr.y);
      a2 += p * bf2f(vr.z); a3 += p * bf2f(vr.w);
    }
    ushort4 o;
    o.x = f2bf(a0); o.y = f2bf(a1); o.z = f2bf(a2); o.w = f2bf(a3);
    *(ushort4*)(ctx + base + t * D_ + d0) = o;
  }
}

// ---------------- other = (sum_n ctx - ctx[3]) / 6 ----------------
__global__ __launch_bounds__(256) void other_kernel(const unsigned short* __restrict__ ctx,
                                                    unsigned short* __restrict__ other) {
  int i = (blockIdx.x * 256 + threadIdx.x) * 4;
  if (i >= BAND_ELEMS) return;
  float s0 = 0.f, s1 = 0.f, s2 = 0.f, s3 = 0.f;
#pragma unroll
  for (int nn = 0; nn < 7; ++nn) {
    if (nn == 3) continue;
    ushort4 c = *(const ushort4*)(ctx + nn * BAND_ELEMS + i);
    s0 += bf2f(c.x); s1 += bf2f(c.y); s2 += bf2f(c.z); s3 += bf2f(c.w);
  }
  const float inv6 = 1.f / 6.f;
  ushort4 o;
  o.x = f2bf(s0 * inv6); o.y = f2bf(s1 * inv6);
  o.z = f2bf(s2 * inv6); o.w = f2bf(s3 * inv6);
  *(ushort4*)(other + i) = o;
}

// ---------------- host launch ----------------
extern "C" void kernel_launch(void* const* d_in, const int* in_sizes, int n_in,
                              void* d_out, int out_size, void* d_ws, size_t ws_size,
                              hipStream_t stream) {
  const float* band[7];
  for (int i = 0; i < 7; ++i) band[i] = (const float*)d_in[i];
  const float* qw = (const float*)d_in[7];   const float* qb = (const float*)d_in[8];
  const float* kw = (const float*)d_in[9];   const float* kb = (const float*)d_in[10];
  const float* vw = (const float*)d_in[11];  const float* vb = (const float*)d_in[12];
  const float* crossw  = (const float*)d_in[13]; const float* crossb  = (const float*)d_in[14];
  const float* crossrw = (const float*)d_in[15]; const float* crossrb = (const float*)d_in[16];
  const float* gatew = (const float*)d_in[17];   const float* gateb = (const float*)d_in[18];
  const float* bridgew = (const float*)d_in[19]; const float* bridgeb = (const float*)d_in[20];

  unsigned short* ws = (unsigned short*)d_ws;
  unsigned short* bands_bf = ws;
  unsigned short* qbf      = bands_bf + 7 * BAND_ELEMS;
  unsigned short* kbf      = qbf + 7 * BAND_ELEMS;
  unsigned short* vbf      = kbf + 7 * BAND_ELEMS;
  unsigned short* ctx      = vbf + 7 * BAND_ELEMS;
  unsigned short* inject   = ctx + 7 * BAND_ELEMS;
  unsigned short* other    = inject + 7 * BAND_ELEMS;
  unsigned short* qw_bf    = other + BAND_ELEMS;
  unsigned short* kw_bf    = qw_bf + 7 * 65536;
  unsigned short* vw_bf    = kw_bf + 7 * 65536;
  unsigned short* crossw_bf  = vw_bf + 7 * 65536;
  unsigned short* crossrw_bf = crossw_bf + 3 * 65536;
  unsigned short* gatew_bf   = crossrw_bf + 3 * 65536;
  unsigned short* bridgew_bf = gatew_bf + 7 * 131072;
  const size_t needed = (size_t)(6 * 7 * BAND_ELEMS + BAND_ELEMS +
                                 3 * 7 * 65536 + 2 * 3 * 65536 + 7 * 131072 + 65536) * 2;
  if (ws_size < needed) return;

  CvtParams cp;
  for (int i = 0; i < 7; ++i) cp.seg[i] = {band[i], bands_bf + i * BAND_ELEMS, BAND_ELEMS};
  cp.seg[7]  = {qw, qw_bf, 7 * 65536};
  cp.seg[8]  = {kw, kw_bf, 7 * 65536};
  cp.seg[9]  = {vw, vw_bf, 7 * 65536};
  cp.seg[10] = {crossw, crossw_bf, 3 * 65536};
  cp.seg[11] = {crossrw, crossrw_bf, 3 * 65536};
  cp.seg[12] = {gatew, gatew_bf, 7 * 131072};
  cp.seg[13] = {bridgew, bridgew_bf, 65536};
  cvt_kernel<<<dim3(BAND_ELEMS / 1024, 14), 256, 0, stream>>>(cp);

  ProjParams pp;
  pp.bands = bands_bf;
  pp.w[0] = qw_bf; pp.w[1] = kw_bf; pp.w[2] = vw_bf;
  pp.bias[0] = qb; pp.bias[1] = kb; pp.bias[2] = vb;
  pp.dst[0] = qbf; pp.dst[1] = kbf; pp.dst[2] = vbf;
  proj_kernel<<<dim3(16, 2, 21), 256, 0, stream>>>(pp);

  attn_kernel<<<dim3(NBAND * B_ * 16), 256, 0, stream>>>(qbf, kbf, vbf, ctx);

  other_kernel<<<dim3(BAND_ELEMS / 1024), 256, 0, stream>>>(ctx, other);

  InjParams ip;
  ip.src[6] = ctx + 0 * BAND_ELEMS; ip.w[6] = crossw_bf + 0 * 65536; ip.bias[6] = crossb + 0 * 256;
  ip.src[5] = ctx + 1 * BAND_ELEMS; ip.w[5] = crossw_bf + 1 * 65536; ip.bias[5] = crossb + 1 * 256;
  ip.src[4] = ctx + 2 * BAND_ELEMS; ip.w[4] = crossw_bf + 2 * 65536; ip.bias[4] = crossb + 2 * 256;
  ip.src[0] = ctx + 6 * BAND_ELEMS; ip.w[0] = crossrw_bf + 0 * 65536; ip.bias[0] = crossrb + 0 * 256;
  ip.src[1] = ctx + 5 * BAND_ELEMS; ip.w[1] = crossrw_bf + 1 * 65536; ip.bias[1] = crossrb + 1 * 256;
  ip.src[2] = ctx + 4 * BAND_ELEMS; ip.w[2] = crossrw_bf + 2 * 65536; ip.bias[2] = crossrb + 2 * 256;
  ip.src[3] = other;                ip.w[3] = bridgew_bf;             ip.bias[3] = bridgeb;
  ip.inject = inject;
  inject_kernel<<<dim3(16, 2, 7), 256, 0, stream>>>(ip);

  GateParams gp;
  gp.bands = bands_bf; gp.inject = inject;
  gp.gatew = gatew_bf; gp.gateb = gateb;
  for (int i = 0; i < 7; ++i) gp.bandf[i] = band[i];
  gp.out = (float*)d_out;
  gate_kernel<<<dim3(16, 4, 7), 256, 0, stream>>>(gp);
}

// Round 3
// 443.810 us; speedup vs baseline: 1.7120x; 1.3357x over previous
//
#include <hip/hip_runtime.h>

#define B_ 8
#define T_ 1024
#define D_ 256
#define NBAND 7
#define MROWS (B_*T_)             // 8192 rows per band
#define BAND_ELEMS (MROWS*D_)     // 2097152

typedef __attribute__((ext_vector_type(8))) short bf16x8;
typedef __attribute__((ext_vector_type(4))) float f32x4;

__device__ __forceinline__ unsigned short f2bf(float f) {
  unsigned int u = __float_as_uint(f);
  u = u + 0x7fffu + ((u >> 16) & 1u);
  return (unsigned short)(u >> 16);
}
__device__ __forceinline__ float bf2f(unsigned short h) {
  return __uint_as_float(((unsigned int)h) << 16);
}

// ---------------- conversion fp32 -> bf16 ----------------
struct CvtSeg { const float* src; unsigned short* dst; int n; };
struct CvtParams { CvtSeg seg[14]; };

__global__ __launch_bounds__(256) void cvt_kernel(CvtParams p) {
  CvtSeg s = p.seg[blockIdx.y];
  int i = (blockIdx.x * 256 + threadIdx.x) * 4;
  if (i >= s.n) return;
  float4 v = *(const float4*)(s.src + i);
  ushort4 o;
  o.x = f2bf(v.x); o.y = f2bf(v.y); o.z = f2bf(v.z); o.w = f2bf(v.w);
  *(ushort4*)(s.dst + i) = o;
}

// =================== m97-style 128x128 LDS-staged GEMM core =================
// Block 256 thr = 4 waves in 2x2; wave computes 64x64 via 4x4 MFMA acc tiles.
// A [M,256] bf16 row-major (Ab supplies k>=256 when TWOA), W [N,NKI*64] bf16
// row-major (torch Linear => y = x @ W^T, so W rows are output cols = MFMA B).
// LDS granule g (16B) of row r stored at slot g^(r&7): frag ds_read_b128 is
// conflict-free; global_load_lds dest = wave base + lane*16 (HW constraint).
template<int NKI, bool TWOA>
__device__ __forceinline__ void gemm128(const unsigned short* __restrict__ Aa,
                                        const unsigned short* __restrict__ Ab,
                                        const unsigned short* __restrict__ W,
                                        int m0, int n0,
                                        unsigned short* a_lds, unsigned short* w_lds,
                                        f32x4 acc[4][4]) {
  const int lane = threadIdx.x & 63, wv = threadIdx.x >> 6;
  const int quad = lane >> 4, l15 = lane & 15;
  const int lrow = lane >> 3;           // 0..7
  const int gsw  = (lane & 7) ^ lrow;   // swizzled global granule for this lane
  const int arow = (wv >> 1) * 64 + l15;
  const int wrow = (wv & 1) * 64 + l15;
  const int s7 = l15 & 7;

#pragma unroll
  for (int ki = 0; ki < NKI; ++ki) {
    const unsigned short* Asrc = (TWOA && ki >= 4) ? Ab : Aa;
    const int kk = (TWOA && ki >= 4) ? (ki - 4) * 64 : ki * 64;
    // stage A tile: 128 rows x 64 k (16KB); wave wv covers rows p*32+wv*8..+8
#pragma unroll
    for (int p = 0; p < 4; ++p) {
      const int r = p * 32 + wv * 8;
      const unsigned short* gp = Asrc + (size_t)(m0 + r + lrow) * 256 + kk + gsw * 8;
      unsigned short* lp = a_lds + r * 64;
      __builtin_amdgcn_global_load_lds((const __attribute__((address_space(1))) void*)gp,
                                       (__attribute__((address_space(3))) void*)lp, 16, 0, 0);
    }
#pragma unroll
    for (int p = 0; p < 4; ++p) {
      const int r = p * 32 + wv * 8;
      const unsigned short* gp = W + (size_t)(n0 + r + lrow) * (NKI * 64) + ki * 64 + gsw * 8;
      unsigned short* lp = w_lds + r * 64;
      __builtin_amdgcn_global_load_lds((const __attribute__((address_space(1))) void*)gp,
                                       (__attribute__((address_space(3))) void*)lp, 16, 0, 0);
    }
    __syncthreads();
#pragma unroll
    for (int kc = 0; kc < 2; ++kc) {
      bf16x8 af[4], wf[4];
#pragma unroll
      for (int rt = 0; rt < 4; ++rt) {
        const int r = arow + rt * 16;
        const int s = (kc * 4 + quad) ^ s7;
        af[rt] = *(const bf16x8*)(a_lds + r * 64 + s * 8);
      }
#pragma unroll
      for (int ct = 0; ct < 4; ++ct) {
        const int r = wrow + ct * 16;
        const int s = (kc * 4 + quad) ^ s7;
        wf[ct] = *(const bf16x8*)(w_lds + r * 64 + s * 8);
      }
#pragma unroll
      for (int rt = 0; rt < 4; ++rt)
#pragma unroll
        for (int ct = 0; ct < 4; ++ct)
          acc[rt][ct] = __builtin_amdgcn_mfma_f32_16x16x32_bf16(af[rt], wf[ct], acc[rt][ct], 0, 0, 0);
    }
    __syncthreads();
  }
}

// ---------------- Q/K/V projection: z = n*3+which ----------------
struct ProjParams {
  const unsigned short* bands;   // [7][8192][256]
  const unsigned short* w[3];    // each [7][256][256]
  const float* bias[3];          // each [7][256] fp32
  unsigned short* dst[3];        // q,k,v [7][8192][256]
};
__global__ __launch_bounds__(256) void proj_kernel(ProjParams p) {
  __shared__ unsigned short a_lds[128 * 64];
  __shared__ unsigned short w_lds[128 * 64];
  const int z = blockIdx.z;
  const int n = z / 3, which = z % 3;
  const unsigned short* A = p.bands + n * BAND_ELEMS;
  const unsigned short* W = p.w[which] + n * D_ * D_;
  const float* bias = p.bias[which] + n * D_;
  unsigned short* Dst = p.dst[which] + n * BAND_ELEMS;
  const int m0 = blockIdx.x * 128, n0 = blockIdx.y * 128;

  f32x4 acc[4][4];
#pragma unroll
  for (int i = 0; i < 4; ++i)
#pragma unroll
    for (int j = 0; j < 4; ++j) acc[i][j] = (f32x4){0.f, 0.f, 0.f, 0.f};
  gemm128<4, false>(A, A, W, m0, n0, a_lds, w_lds, acc);

  const int lane = threadIdx.x & 63, wv = threadIdx.x >> 6;
  const int quad = lane >> 4, l15 = lane & 15;
  const int rowbase = m0 + (wv >> 1) * 64 + quad * 4;
  const int colbase = n0 + (wv & 1) * 64;
#pragma unroll
  for (int ct = 0; ct < 4; ++ct) {
    const int col = colbase + ct * 16 + l15;
    const float b = bias[col];
#pragma unroll
    for (int rt = 0; rt < 4; ++rt)
#pragma unroll
      for (int r = 0; r < 4; ++r)
        Dst[(size_t)(rowbase + rt * 16 + r) * 256 + col] = f2bf(acc[rt][ct][r] + b);
  }
}

// ---------------- inject projections (cross / crossr / bridge), z = band ----
struct InjParams {
  const unsigned short* src[7];
  const unsigned short* w[7];
  const float* bias[7];
  unsigned short* inject;
};
__global__ __launch_bounds__(256) void inject_kernel(InjParams p) {
  __shared__ unsigned short a_lds[128 * 64];
  __shared__ unsigned short w_lds[128 * 64];
  const int i = blockIdx.z;
  const unsigned short* A = p.src[i];
  const unsigned short* W = p.w[i];
  const float* bias = p.bias[i];
  unsigned short* Dst = p.inject + i * BAND_ELEMS;
  const int m0 = blockIdx.x * 128, n0 = blockIdx.y * 128;

  f32x4 acc[4][4];
#pragma unroll
  for (int a = 0; a < 4; ++a)
#pragma unroll
    for (int b = 0; b < 4; ++b) acc[a][b] = (f32x4){0.f, 0.f, 0.f, 0.f};
  gemm128<4, false>(A, A, W, m0, n0, a_lds, w_lds, acc);

  const int lane = threadIdx.x & 63, wv = threadIdx.x >> 6;
  const int quad = lane >> 4, l15 = lane & 15;
  const int rowbase = m0 + (wv >> 1) * 64 + quad * 4;
  const int colbase = n0 + (wv & 1) * 64;
#pragma unroll
  for (int ct = 0; ct < 4; ++ct) {
    const int col = colbase + ct * 16 + l15;
    const float b = bias[col];
#pragma unroll
    for (int rt = 0; rt < 4; ++rt)
#pragma unroll
      for (int r = 0; r < 4; ++r)
        Dst[(size_t)(rowbase + rt * 16 + r) * 256 + col] = f2bf(acc[rt][ct][r] + b);
  }
}

// ---------------- gate + output: K=512 (band | inject) ----------------
struct GateParams {
  const unsigned short* bands;   // bf16 [7][8192][256]
  const unsigned short* inject;  // bf16 [7][8192][256]
  const unsigned short* gatew;   // bf16 [7][256][512]
  const float* gateb;            // fp32 [7][256]
  const float* bandf[7];         // original fp32 bands
  float* out;                    // [7][8192][256]
};
__global__ __launch_bounds__(256) void gate_kernel(GateParams p) {
  __shared__ unsigned short a_lds[128 * 64];
  __shared__ unsigned short w_lds[128 * 64];
  const int i = blockIdx.z;
  const unsigned short* A0 = p.bands + i * BAND_ELEMS;
  const unsigned short* A1 = p.inject + i * BAND_ELEMS;
  const unsigned short* W = p.gatew + i * D_ * 512;
  const float* bias = p.gateb + i * D_;
  const float* bf = p.bandf[i];
  float* out = p.out + i * BAND_ELEMS;
  const int m0 = blockIdx.x * 128, n0 = blockIdx.y * 128;

  f32x4 acc[4][4];
#pragma unroll
  for (int a = 0; a < 4; ++a)
#pragma unroll
    for (int b = 0; b < 4; ++b) acc[a][b] = (f32x4){0.f, 0.f, 0.f, 0.f};
  gemm128<8, true>(A0, A1, W, m0, n0, a_lds, w_lds, acc);

  const int lane = threadIdx.x & 63, wv = threadIdx.x >> 6;
  const int quad = lane >> 4, l15 = lane & 15;
  const int rowbase = m0 + (wv >> 1) * 64 + quad * 4;
  const int colbase = n0 + (wv & 1) * 64;
#pragma unroll
  for (int ct = 0; ct < 4; ++ct) {
    const int col = colbase + ct * 16 + l15;
    const float b = bias[col];
#pragma unroll
    for (int rt = 0; rt < 4; ++rt)
#pragma unroll
      for (int r = 0; r < 4; ++r) {
        const size_t idx = (size_t)(rowbase + rt * 16 + r) * 256 + col;
        const float g = 1.f / (1.f + __expf(-(acc[rt][ct][r] + b)));
        const float inj = bf2f(A1[idx]);
        out[idx] = bf[idx] + g * inj;
      }
  }
}

// ============== attention: MFMA scores + softmax + scalar PV ===============
__global__ __launch_bounds__(256) void attn_kernel(const unsigned short* __restrict__ q,
                                                   const unsigned short* __restrict__ k,
                                                   const unsigned short* __restrict__ v,
                                                   unsigned short* __restrict__ ctx) {
  __shared__ float plds[4][16][148];
  const int wv = threadIdx.x >> 6, lane = threadIdx.x & 63;
  const int quad = lane >> 4, l15 = lane & 15;
  const int bid = blockIdx.x;              // 7*8*16 = 896
  const int n = bid >> 7;
  const int b = (bid >> 4) & 7;
  const int qblk = bid & 15;
  const int t0 = qblk * 64 + wv * 16;
  const int w = 1 << ((0x2344567u >> (4 * n)) & 0xFu);
  const int base = ((n * B_ + b) * T_) * D_;

  int klo_key = t0 - w + 1; if (klo_key < 0) klo_key = 0;
  const int kt_lo = klo_key >> 4;
  const int kt_hi = t0 >> 4;
  const int ntiles = kt_hi - kt_lo + 1;    // <= 9

  bf16x8 qf[8];
  {
    const unsigned short* qr = q + base + (t0 + l15) * D_ + quad * 8;
#pragma unroll
    for (int kc = 0; kc < 8; ++kc) qf[kc] = *(const bf16x8*)(qr + kc * 32);
  }

  f32x4 s[9];
#pragma unroll
  for (int it = 0; it < 9; ++it) {
    if (it < ntiles) {
      const int kt = kt_lo + it;
      const unsigned short* kr = k + base + (kt * 16 + l15) * D_ + quad * 8;
      f32x4 acc = (f32x4){0.f,0.f,0.f,0.f};
#pragma unroll
      for (int kc = 0; kc < 8; ++kc) {
        bf16x8 kf = *(const bf16x8*)(kr + kc * 32);
        acc = __builtin_amdgcn_mfma_f32_16x16x32_bf16(qf[kc], kf, acc, 0, 0, 0);
      }
      s[it] = acc;
    }
  }

#pragma unroll
  for (int r = 0; r < 4; ++r) {
    const int i = t0 + quad * 4 + r;
    float m = -1e30f;
#pragma unroll
    for (int it = 0; it < 9; ++it) {
      if (it < ntiles) {
        const int j = (kt_lo + it) * 16 + l15;
        float val = s[it][r] * 0.0625f;
        val = (j <= i && j > i - w) ? val : -1e30f;
        s[it][r] = val;
        m = fmaxf(m, val);
      }
    }
#pragma unroll
    for (int off = 8; off; off >>= 1) m = fmaxf(m, __shfl_xor(m, off, 64));
    float l = 0.f;
#pragma unroll
    for (int it = 0; it < 9; ++it) {
      if (it < ntiles) {
        float e = __expf(s[it][r] - m);
        s[it][r] = e;
        l += e;
      }
    }
#pragma unroll
    for (int off = 8; off; off >>= 1) l += __shfl_xor(l, off, 64);
    const float inv = 1.f / l;
#pragma unroll
    for (int it = 0; it < 9; ++it)
      if (it < ntiles)
        plds[wv][quad * 4 + r][it * 16 + l15] = s[it][r] * inv;
  }
  __syncthreads();

  const int d0 = lane * 4;
  const int cbase = kt_lo * 16;
  for (int r16 = 0; r16 < 16; ++r16) {
    const int t = t0 + r16;
    int jlo = t - w + 1; if (jlo < 0) jlo = 0;
    float a0 = 0.f, a1 = 0.f, a2 = 0.f, a3 = 0.f;
    const float* prow = plds[wv][r16];
#pragma unroll 4
    for (int j = jlo; j <= t; ++j) {
      const float p = prow[j - cbase];
      ushort4 vr = *(const ushort4*)(v + base + j * D_ + d0);
      a0 += p * bf2f(vr.x); a1 += p * bf2f(vr.y);
      a2 += p * bf2f(vr.z); a3 += p * bf2f(vr.w);
    }
    ushort4 o;
    o.x = f2bf(a0); o.y = f2bf(a1); o.z = f2bf(a2); o.w = f2bf(a3);
    *(ushort4*)(ctx + base + t * D_ + d0) = o;
  }
}

// ---------------- other = (sum_n ctx - ctx[3]) / 6 ----------------
__global__ __launch_bounds__(256) void other_kernel(const unsigned short* __restrict__ ctx,
                                                    unsigned short* __restrict__ other) {
  int i = (blockIdx.x * 256 + threadIdx.x) * 4;
  if (i >= BAND_ELEMS) return;
  float s0 = 0.f, s1 = 0.f, s2 = 0.f, s3 = 0.f;
#pragma unroll
  for (int nn = 0; nn < 7; ++nn) {
    if (nn == 3) continue;
    ushort4 c = *(const ushort4*)(ctx + nn * BAND_ELEMS + i);
    s0 += bf2f(c.x); s1 += bf2f(c.y); s2 += bf2f(c.z); s3 += bf2f(c.w);
  }
  const float inv6 = 1.f / 6.f;
  ushort4 o;
  o.x = f2bf(s0 * inv6); o.y = f2bf(s1 * inv6);
  o.z = f2bf(s2 * inv6); o.w = f2bf(s3 * inv6);
  *(ushort4*)(other + i) = o;
}

// ---------------- host launch ----------------
extern "C" void kernel_launch(void* const* d_in, const int* in_sizes, int n_in,
                              void* d_out, int out_size, void* d_ws, size_t ws_size,
                              hipStream_t stream) {
  const float* band[7];
  for (int i = 0; i < 7; ++i) band[i] = (const float*)d_in[i];
  const float* qw = (const float*)d_in[7];   const float* qb = (const float*)d_in[8];
  const float* kw = (const float*)d_in[9];   const float* kb = (const float*)d_in[10];
  const float* vw = (const float*)d_in[11];  const float* vb = (const float*)d_in[12];
  const float* crossw  = (const float*)d_in[13]; const float* crossb  = (const float*)d_in[14];
  const float* crossrw = (const float*)d_in[15]; const float* crossrb = (const float*)d_in[16];
  const float* gatew = (const float*)d_in[17];   const float* gateb = (const float*)d_in[18];
  const float* bridgew = (const float*)d_in[19]; const float* bridgeb = (const float*)d_in[20];

  unsigned short* ws = (unsigned short*)d_ws;
  unsigned short* bands_bf = ws;
  unsigned short* qbf      = bands_bf + 7 * BAND_ELEMS;
  unsigned short* kbf      = qbf + 7 * BAND_ELEMS;
  unsigned short* vbf      = kbf + 7 * BAND_ELEMS;
  unsigned short* ctx      = vbf + 7 * BAND_ELEMS;
  unsigned short* inject   = ctx + 7 * BAND_ELEMS;
  unsigned short* other    = inject + 7 * BAND_ELEMS;
  unsigned short* qw_bf    = other + BAND_ELEMS;
  unsigned short* kw_bf    = qw_bf + 7 * 65536;
  unsigned short* vw_bf    = kw_bf + 7 * 65536;
  unsigned short* crossw_bf  = vw_bf + 7 * 65536;
  unsigned short* crossrw_bf = crossw_bf + 3 * 65536;
  unsigned short* gatew_bf   = crossrw_bf + 3 * 65536;
  unsigned short* bridgew_bf = gatew_bf + 7 * 131072;
  const size_t needed = (size_t)(6 * 7 * BAND_ELEMS + BAND_ELEMS +
                                 3 * 7 * 65536 + 2 * 3 * 65536 + 7 * 131072 + 65536) * 2;
  if (ws_size < needed) return;

  CvtParams cp;
  for (int i = 0; i < 7; ++i) cp.seg[i] = {band[i], bands_bf + i * BAND_ELEMS, BAND_ELEMS};
  cp.seg[7]  = {qw, qw_bf, 7 * 65536};
  cp.seg[8]  = {kw, kw_bf, 7 * 65536};
  cp.seg[9]  = {vw, vw_bf, 7 * 65536};
  cp.seg[10] = {crossw, crossw_bf, 3 * 65536};
  cp.seg[11] = {crossrw, crossrw_bf, 3 * 65536};
  cp.seg[12] = {gatew, gatew_bf, 7 * 131072};
  cp.seg[13] = {bridgew, bridgew_bf, 65536};
  cvt_kernel<<<dim3(BAND_ELEMS / 1024, 14), 256, 0, stream>>>(cp);

  ProjParams pp;
  pp.bands = bands_bf;
  pp.w[0] = qw_bf; pp.w[1] = kw_bf; pp.w[2] = vw_bf;
  pp.bias[0] = qb; pp.bias[1] = kb; pp.bias[2] = vb;
  pp.dst[0] = qbf; pp.dst[1] = kbf; pp.dst[2] = vbf;
  proj_kernel<<<dim3(64, 2, 21), 256, 0, stream>>>(pp);

  attn_kernel<<<dim3(NBAND * B_ * 16), 256, 0, stream>>>(qbf, kbf, vbf, ctx);

  other_kernel<<<dim3(BAND_ELEMS / 1024), 256, 0, stream>>>(ctx, other);

  InjParams ip;
  ip.src[6] = ctx + 0 * BAND_ELEMS; ip.w[6] = crossw_bf + 0 * 65536; ip.bias[6] = crossb + 0 * 256;
  ip.src[5] = ctx + 1 * BAND_ELEMS; ip.w[5] = crossw_bf + 1 * 65536; ip.bias[5] = crossb + 1 * 256;
  ip.src[4] = ctx + 2 * BAND_ELEMS; ip.w[4] = crossw_bf + 2 * 65536; ip.bias[4] = crossb + 2 * 256;
  ip.src[0] = ctx + 6 * BAND_ELEMS; ip.w[0] = crossrw_bf + 0 * 65536; ip.bias[0] = crossrb + 0 * 256;
  ip.src[1] = ctx + 5 * BAND_ELEMS; ip.w[1] = crossrw_bf + 1 * 65536; ip.bias[1] = crossrb + 1 * 256;
  ip.src[2] = ctx + 4 * BAND_ELEMS; ip.w[2] = crossrw_bf + 2 * 65536; ip.bias[2] = crossrb + 2 * 256;
  ip.src[3] = other;                ip.w[3] = bridgew_bf;             ip.bias[3] = bridgeb;
  ip.inject = inject;
  inject_kernel<<<dim3(64, 2, 7), 256, 0, stream>>>(ip);

  GateParams gp;
  gp.bands = bands_bf; gp.inject = inject;
  gp.gatew = gatew_bf; gp.gateb = gateb;
  for (int i = 0; i < 7; ++i) gp.bandf[i] = band[i];
  gp.out = (float*)d_out;
  gate_kernel<<<dim3(64, 2, 7), 256, 0, stream>>>(gp);
}

// Round 4
// 379.463 us; speedup vs baseline: 2.0023x; 1.1696x over previous
//
#include <hip/hip_runtime.h>

#define B_ 8
#define T_ 1024
#define D_ 256
#define NBAND 7
#define MROWS (B_*T_)             // 8192 rows per band
#define BAND_ELEMS (MROWS*D_)     // 2097152

typedef __attribute__((ext_vector_type(8))) short bf16x8;
typedef __attribute__((ext_vector_type(4))) float f32x4;

__device__ __forceinline__ unsigned short f2bf(float f) {
  unsigned int u = __float_as_uint(f);
  u = u + 0x7fffu + ((u >> 16) & 1u);
  return (unsigned short)(u >> 16);
}
__device__ __forceinline__ float bf2f(unsigned short h) {
  return __uint_as_float(((unsigned int)h) << 16);
}

// ---------------- conversion fp32 -> bf16 ----------------
struct CvtSeg { const float* src; unsigned short* dst; int n; };
struct CvtParams { CvtSeg seg[14]; };

__global__ __launch_bounds__(256) void cvt_kernel(CvtParams p) {
  CvtSeg s = p.seg[blockIdx.y];
  int i = (blockIdx.x * 256 + threadIdx.x) * 4;
  if (i >= s.n) return;
  float4 v = *(const float4*)(s.src + i);
  ushort4 o;
  o.x = f2bf(v.x); o.y = f2bf(v.y); o.z = f2bf(v.z); o.w = f2bf(v.w);
  *(ushort4*)(s.dst + i) = o;
}

// =================== m97-style 128x128 LDS-staged GEMM core =================
template<int NKI, bool TWOA>
__device__ __forceinline__ void gemm128(const unsigned short* __restrict__ Aa,
                                        const unsigned short* __restrict__ Ab,
                                        const unsigned short* __restrict__ W,
                                        int m0, int n0,
                                        unsigned short* a_lds, unsigned short* w_lds,
                                        f32x4 acc[4][4]) {
  const int lane = threadIdx.x & 63, wv = threadIdx.x >> 6;
  const int quad = lane >> 4, l15 = lane & 15;
  const int lrow = lane >> 3;           // 0..7
  const int gsw  = (lane & 7) ^ lrow;   // swizzled global granule for this lane
  const int arow = (wv >> 1) * 64 + l15;
  const int wrow = (wv & 1) * 64 + l15;
  const int s7 = l15 & 7;

#pragma unroll
  for (int ki = 0; ki < NKI; ++ki) {
    const unsigned short* Asrc = (TWOA && ki >= 4) ? Ab : Aa;
    const int kk = (TWOA && ki >= 4) ? (ki - 4) * 64 : ki * 64;
#pragma unroll
    for (int p = 0; p < 4; ++p) {
      const int r = p * 32 + wv * 8;
      const unsigned short* gp = Asrc + (size_t)(m0 + r + lrow) * 256 + kk + gsw * 8;
      unsigned short* lp = a_lds + r * 64;
      __builtin_amdgcn_global_load_lds((const __attribute__((address_space(1))) void*)gp,
                                       (__attribute__((address_space(3))) void*)lp, 16, 0, 0);
    }
#pragma unroll
    for (int p = 0; p < 4; ++p) {
      const int r = p * 32 + wv * 8;
      const unsigned short* gp = W + (size_t)(n0 + r + lrow) * (NKI * 64) + ki * 64 + gsw * 8;
      unsigned short* lp = w_lds + r * 64;
      __builtin_amdgcn_global_load_lds((const __attribute__((address_space(1))) void*)gp,
                                       (__attribute__((address_space(3))) void*)lp, 16, 0, 0);
    }
    __syncthreads();
#pragma unroll
    for (int kc = 0; kc < 2; ++kc) {
      bf16x8 af[4], wf[4];
#pragma unroll
      for (int rt = 0; rt < 4; ++rt) {
        const int r = arow + rt * 16;
        const int s = (kc * 4 + quad) ^ s7;
        af[rt] = *(const bf16x8*)(a_lds + r * 64 + s * 8);
      }
#pragma unroll
      for (int ct = 0; ct < 4; ++ct) {
        const int r = wrow + ct * 16;
        const int s = (kc * 4 + quad) ^ s7;
        wf[ct] = *(const bf16x8*)(w_lds + r * 64 + s * 8);
      }
#pragma unroll
      for (int rt = 0; rt < 4; ++rt)
#pragma unroll
        for (int ct = 0; ct < 4; ++ct)
          acc[rt][ct] = __builtin_amdgcn_mfma_f32_16x16x32_bf16(af[rt], wf[ct], acc[rt][ct], 0, 0, 0);
    }
    __syncthreads();
  }
}

// ---------------- Q/K/V projection: z = n*3+which ----------------
struct ProjParams {
  const unsigned short* bands;   // [7][8192][256]
  const unsigned short* w[3];    // each [7][256][256]
  const float* bias[3];          // each [7][256] fp32
  unsigned short* dst[3];        // q,k,v [7][8192][256]
};
__global__ __launch_bounds__(256) void proj_kernel(ProjParams p) {
  __shared__ unsigned short a_lds[128 * 64];
  __shared__ unsigned short w_lds[128 * 64];
  const int z = blockIdx.z;
  const int n = z / 3, which = z % 3;
  const unsigned short* A = p.bands + n * BAND_ELEMS;
  const unsigned short* W = p.w[which] + n * D_ * D_;
  const float* bias = p.bias[which] + n * D_;
  unsigned short* Dst = p.dst[which] + n * BAND_ELEMS;
  const int m0 = blockIdx.x * 128, n0 = blockIdx.y * 128;

  f32x4 acc[4][4];
#pragma unroll
  for (int i = 0; i < 4; ++i)
#pragma unroll
    for (int j = 0; j < 4; ++j) acc[i][j] = (f32x4){0.f, 0.f, 0.f, 0.f};
  gemm128<4, false>(A, A, W, m0, n0, a_lds, w_lds, acc);

  const int lane = threadIdx.x & 63, wv = threadIdx.x >> 6;
  const int quad = lane >> 4, l15 = lane & 15;
  const int rowbase = m0 + (wv >> 1) * 64 + quad * 4;
  const int colbase = n0 + (wv & 1) * 64;
#pragma unroll
  for (int ct = 0; ct < 4; ++ct) {
    const int col = colbase + ct * 16 + l15;
    const float b = bias[col];
#pragma unroll
    for (int rt = 0; rt < 4; ++rt)
#pragma unroll
      for (int r = 0; r < 4; ++r)
        Dst[(size_t)(rowbase + rt * 16 + r) * 256 + col] = f2bf(acc[rt][ct][r] + b);
  }
}

// ---------------- inject projections (cross / crossr / bridge), z = band ----
struct InjParams {
  const unsigned short* src[7];
  const unsigned short* w[7];
  const float* bias[7];
  unsigned short* inject;
};
__global__ __launch_bounds__(256) void inject_kernel(InjParams p) {
  __shared__ unsigned short a_lds[128 * 64];
  __shared__ unsigned short w_lds[128 * 64];
  const int i = blockIdx.z;
  const unsigned short* A = p.src[i];
  const unsigned short* W = p.w[i];
  const float* bias = p.bias[i];
  unsigned short* Dst = p.inject + i * BAND_ELEMS;
  const int m0 = blockIdx.x * 128, n0 = blockIdx.y * 128;

  f32x4 acc[4][4];
#pragma unroll
  for (int a = 0; a < 4; ++a)
#pragma unroll
    for (int b = 0; b < 4; ++b) acc[a][b] = (f32x4){0.f, 0.f, 0.f, 0.f};
  gemm128<4, false>(A, A, W, m0, n0, a_lds, w_lds, acc);

  const int lane = threadIdx.x & 63, wv = threadIdx.x >> 6;
  const int quad = lane >> 4, l15 = lane & 15;
  const int rowbase = m0 + (wv >> 1) * 64 + quad * 4;
  const int colbase = n0 + (wv & 1) * 64;
#pragma unroll
  for (int ct = 0; ct < 4; ++ct) {
    const int col = colbase + ct * 16 + l15;
    const float b = bias[col];
#pragma unroll
    for (int rt = 0; rt < 4; ++rt)
#pragma unroll
      for (int r = 0; r < 4; ++r)
        Dst[(size_t)(rowbase + rt * 16 + r) * 256 + col] = f2bf(acc[rt][ct][r] + b);
  }
}

// ---------------- gate + output: K=512 (band | inject) ----------------
struct GateParams {
  const unsigned short* bands;   // bf16 [7][8192][256]
  const unsigned short* inject;  // bf16 [7][8192][256]
  const unsigned short* gatew;   // bf16 [7][256][512]
  const float* gateb;            // fp32 [7][256]
  const float* bandf[7];         // original fp32 bands
  float* out;                    // [7][8192][256]
};
__global__ __launch_bounds__(256) void gate_kernel(GateParams p) {
  __shared__ unsigned short a_lds[128 * 64];
  __shared__ unsigned short w_lds[128 * 64];
  const int i = blockIdx.z;
  const unsigned short* A0 = p.bands + i * BAND_ELEMS;
  const unsigned short* A1 = p.inject + i * BAND_ELEMS;
  const unsigned short* W = p.gatew + i * D_ * 512;
  const float* bias = p.gateb + i * D_;
  const float* bf = p.bandf[i];
  float* out = p.out + i * BAND_ELEMS;
  const int m0 = blockIdx.x * 128, n0 = blockIdx.y * 128;

  f32x4 acc[4][4];
#pragma unroll
  for (int a = 0; a < 4; ++a)
#pragma unroll
    for (int b = 0; b < 4; ++b) acc[a][b] = (f32x4){0.f, 0.f, 0.f, 0.f};
  gemm128<8, true>(A0, A1, W, m0, n0, a_lds, w_lds, acc);

  const int lane = threadIdx.x & 63, wv = threadIdx.x >> 6;
  const int quad = lane >> 4, l15 = lane & 15;
  const int rowbase = m0 + (wv >> 1) * 64 + quad * 4;
  const int colbase = n0 + (wv & 1) * 64;
#pragma unroll
  for (int ct = 0; ct < 4; ++ct) {
    const int col = colbase + ct * 16 + l15;
    const float b = bias[col];
#pragma unroll
    for (int rt = 0; rt < 4; ++rt)
#pragma unroll
      for (int r = 0; r < 4; ++r) {
        const size_t idx = (size_t)(rowbase + rt * 16 + r) * 256 + col;
        const float g = 1.f / (1.f + __expf(-(acc[rt][ct][r] + b)));
        const float inj = bf2f(A1[idx]);
        out[idx] = bf[idx] + g * inj;
      }
  }
}

// ============== attention: MFMA scores + softmax + inverted scalar PV =======
// P staged in LDS transposed [key][row] so the PV loop reads 16 row-values as
// 4x ds_read_b128 broadcast per key; V row loaded ONCE per key (was 16x).
__global__ __launch_bounds__(256) void attn_kernel(const unsigned short* __restrict__ q,
                                                   const unsigned short* __restrict__ k,
                                                   const unsigned short* __restrict__ v,
                                                   unsigned short* __restrict__ ctx) {
  __shared__ float plds[4][144][16];    // per-wave P^T: [key][qrow]
  const int wv = threadIdx.x >> 6, lane = threadIdx.x & 63;
  const int quad = lane >> 4, l15 = lane & 15;
  const int bid = blockIdx.x;              // 7*8*16 = 896
  const int n = bid >> 7;
  const int b = (bid >> 4) & 7;
  const int qblk = bid & 15;
  const int t0 = qblk * 64 + wv * 16;
  const int w = 1 << ((0x2344567u >> (4 * n)) & 0xFu);
  const int base = ((n * B_ + b) * T_) * D_;

  int klo_key = t0 - w + 1; if (klo_key < 0) klo_key = 0;
  const int kt_lo = klo_key >> 4;
  const int kt_hi = t0 >> 4;
  const int ntiles = kt_hi - kt_lo + 1;    // <= 9

  // Q fragments (A layout: m=l15, k=quad*8+j within each 32-chunk)
  bf16x8 qf[8];
  {
    const unsigned short* qr = q + base + (t0 + l15) * D_ + quad * 8;
#pragma unroll
    for (int kc = 0; kc < 8; ++kc) qf[kc] = *(const bf16x8*)(qr + kc * 32);
  }

  // scores: s[it] C layout (col=l15 -> key, row=quad*4+r -> query)
  f32x4 s[9];
#pragma unroll
  for (int it = 0; it < 9; ++it) {
    if (it < ntiles) {
      const int kt = kt_lo + it;
      const unsigned short* kr = k + base + (kt * 16 + l15) * D_ + quad * 8;
      f32x4 acc = (f32x4){0.f,0.f,0.f,0.f};
#pragma unroll
      for (int kc = 0; kc < 8; ++kc) {
        bf16x8 kf = *(const bf16x8*)(kr + kc * 32);
        acc = __builtin_amdgcn_mfma_f32_16x16x32_bf16(qf[kc], kf, acc, 0, 0, 0);
      }
      s[it] = acc;
    }
  }

  // mask + softmax per C-row; write normalized P^T ([key][row]) to LDS.
  // Masked entries become exact 0 => PV loop needs no window test.
#pragma unroll
  for (int r = 0; r < 4; ++r) {
    const int i = t0 + quad * 4 + r;
    float m = -1e30f;
#pragma unroll
    for (int it = 0; it < 9; ++it) {
      if (it < ntiles) {
        const int j = (kt_lo + it) * 16 + l15;
        float val = s[it][r] * 0.0625f;              // 1/sqrt(256)
        val = (j <= i && j > i - w) ? val : -1e30f;
        s[it][r] = val;
        m = fmaxf(m, val);
      }
    }
#pragma unroll
    for (int off = 8; off; off >>= 1) m = fmaxf(m, __shfl_xor(m, off, 64));
    float l = 0.f;
#pragma unroll
    for (int it = 0; it < 9; ++it) {
      if (it < ntiles) {
        float e = __expf(s[it][r] - m);
        s[it][r] = e;
        l += e;
      }
    }
#pragma unroll
    for (int off = 8; off; off >>= 1) l += __shfl_xor(l, off, 64);
    const float inv = 1.f / l;
#pragma unroll
    for (int it = 0; it < 9; ++it)
      if (it < ntiles)
        plds[wv][it * 16 + l15][quad * 4 + r] = s[it][r] * inv;
  }
  __syncthreads();

  // inverted PV: loop keys once; 16 row-accumulators live in registers.
  const int d0 = lane * 4;
  const int cbase = kt_lo * 16;
  const int njj = ntiles * 16;
  float a0[16], a1[16], a2[16], a3[16];
#pragma unroll
  for (int r = 0; r < 16; ++r) { a0[r] = 0.f; a1[r] = 0.f; a2[r] = 0.f; a3[r] = 0.f; }
  const float* pbase = &plds[wv][0][0];
  const unsigned short* vptr = v + base + (size_t)cbase * D_ + d0;
  for (int jj = 0; jj < njj; ++jj) {
    ushort4 vr = *(const ushort4*)(vptr + (size_t)jj * D_);
    const float v0 = bf2f(vr.x), v1 = bf2f(vr.y), v2 = bf2f(vr.z), v3 = bf2f(vr.w);
    float pv[16];
    *(float4*)(pv + 0)  = *(const float4*)(pbase + jj * 16 + 0);
    *(float4*)(pv + 4)  = *(const float4*)(pbase + jj * 16 + 4);
    *(float4*)(pv + 8)  = *(const float4*)(pbase + jj * 16 + 8);
    *(float4*)(pv + 12) = *(const float4*)(pbase + jj * 16 + 12);
#pragma unroll
    for (int r = 0; r < 16; ++r) {
      a0[r] += pv[r] * v0; a1[r] += pv[r] * v1;
      a2[r] += pv[r] * v2; a3[r] += pv[r] * v3;
    }
  }
#pragma unroll
  for (int r = 0; r < 16; ++r) {
    ushort4 o;
    o.x = f2bf(a0[r]); o.y = f2bf(a1[r]); o.z = f2bf(a2[r]); o.w = f2bf(a3[r]);
    *(ushort4*)(ctx + base + (size_t)(t0 + r) * D_ + d0) = o;
  }
}

// ---------------- other = (sum_n ctx - ctx[3]) / 6 ----------------
__global__ __launch_bounds__(256) void other_kernel(const unsigned short* __restrict__ ctx,
                                                    unsigned short* __restrict__ other) {
  int i = (blockIdx.x * 256 + threadIdx.x) * 4;
  if (i >= BAND_ELEMS) return;
  float s0 = 0.f, s1 = 0.f, s2 = 0.f, s3 = 0.f;
#pragma unroll
  for (int nn = 0; nn < 7; ++nn) {
    if (nn == 3) continue;
    ushort4 c = *(const ushort4*)(ctx + nn * BAND_ELEMS + i);
    s0 += bf2f(c.x); s1 += bf2f(c.y); s2 += bf2f(c.z); s3 += bf2f(c.w);
  }
  const float inv6 = 1.f / 6.f;
  ushort4 o;
  o.x = f2bf(s0 * inv6); o.y = f2bf(s1 * inv6);
  o.z = f2bf(s2 * inv6); o.w = f2bf(s3 * inv6);
  *(ushort4*)(other + i) = o;
}

// ---------------- host launch ----------------
extern "C" void kernel_launch(void* const* d_in, const int* in_sizes, int n_in,
                              void* d_out, int out_size, void* d_ws, size_t ws_size,
                              hipStream_t stream) {
  const float* band[7];
  for (int i = 0; i < 7; ++i) band[i] = (const float*)d_in[i];
  const float* qw = (const float*)d_in[7];   const float* qb = (const float*)d_in[8];
  const float* kw = (const float*)d_in[9];   const float* kb = (const float*)d_in[10];
  const float* vw = (const float*)d_in[11];  const float* vb = (const float*)d_in[12];
  const float* crossw  = (const float*)d_in[13]; const float* crossb  = (const float*)d_in[14];
  const float* crossrw = (const float*)d_in[15]; const float* crossrb = (const float*)d_in[16];
  const float* gatew = (const float*)d_in[17];   const float* gateb = (const float*)d_in[18];
  const float* bridgew = (const float*)d_in[19]; const float* bridgeb = (const float*)d_in[20];

  unsigned short* ws = (unsigned short*)d_ws;
  unsigned short* bands_bf = ws;
  unsigned short* qbf      = bands_bf + 7 * BAND_ELEMS;
  unsigned short* kbf      = qbf + 7 * BAND_ELEMS;
  unsigned short* vbf      = kbf + 7 * BAND_ELEMS;
  unsigned short* ctx      = vbf + 7 * BAND_ELEMS;
  unsigned short* inject   = ctx + 7 * BAND_ELEMS;
  unsigned short* other    = inject + 7 * BAND_ELEMS;
  unsigned short* qw_bf    = other + BAND_ELEMS;
  unsigned short* kw_bf    = qw_bf + 7 * 65536;
  unsigned short* vw_bf    = kw_bf + 7 * 65536;
  unsigned short* crossw_bf  = vw_bf + 7 * 65536;
  unsigned short* crossrw_bf = crossw_bf + 3 * 65536;
  unsigned short* gatew_bf   = crossrw_bf + 3 * 65536;
  unsigned short* bridgew_bf = gatew_bf + 7 * 131072;
  const size_t needed = (size_t)(6 * 7 * BAND_ELEMS + BAND_ELEMS +
                                 3 * 7 * 65536 + 2 * 3 * 65536 + 7 * 131072 + 65536) * 2;
  if (ws_size < needed) return;

  CvtParams cp;
  for (int i = 0; i < 7; ++i) cp.seg[i] = {band[i], bands_bf + i * BAND_ELEMS, BAND_ELEMS};
  cp.seg[7]  = {qw, qw_bf, 7 * 65536};
  cp.seg[8]  = {kw, kw_bf, 7 * 65536};
  cp.seg[9]  = {vw, vw_bf, 7 * 65536};
  cp.seg[10] = {crossw, crossw_bf, 3 * 65536};
  cp.seg[11] = {crossrw, crossrw_bf, 3 * 65536};
  cp.seg[12] = {gatew, gatew_bf, 7 * 131072};
  cp.seg[13] = {bridgew, bridgew_bf, 65536};
  cvt_kernel<<<dim3(BAND_ELEMS / 1024, 14), 256, 0, stream>>>(cp);

  ProjParams pp;
  pp.bands = bands_bf;
  pp.w[0] = qw_bf; pp.w[1] = kw_bf; pp.w[2] = vw_bf;
  pp.bias[0] = qb; pp.bias[1] = kb; pp.bias[2] = vb;
  pp.dst[0] = qbf; pp.dst[1] = kbf; pp.dst[2] = vbf;
  proj_kernel<<<dim3(64, 2, 21), 256, 0, stream>>>(pp);

  attn_kernel<<<dim3(NBAND * B_ * 16), 256, 0, stream>>>(qbf, kbf, vbf, ctx);

  other_kernel<<<dim3(BAND_ELEMS / 1024), 256, 0, stream>>>(ctx, other);

  InjParams ip;
  ip.src[6] = ctx + 0 * BAND_ELEMS; ip.w[6] = crossw_bf + 0 * 65536; ip.bias[6] = crossb + 0 * 256;
  ip.src[5] = ctx + 1 * BAND_ELEMS; ip.w[5] = crossw_bf + 1 * 65536; ip.bias[5] = crossb + 1 * 256;
  ip.src[4] = ctx + 2 * BAND_ELEMS; ip.w[4] = crossw_bf + 2 * 65536; ip.bias[4] = crossb + 2 * 256;
  ip.src[0] = ctx + 6 * BAND_ELEMS; ip.w[0] = crossrw_bf + 0 * 65536; ip.bias[0] = crossrb + 0 * 256;
  ip.src[1] = ctx + 5 * BAND_ELEMS; ip.w[1] = crossrw_bf + 1 * 65536; ip.bias[1] = crossrb + 1 * 256;
  ip.src[2] = ctx + 4 * BAND_ELEMS; ip.w[2] = crossrw_bf + 2 * 65536; ip.bias[2] = crossrb + 2 * 256;
  ip.src[3] = other;                ip.w[3] = bridgew_bf;             ip.bias[3] = bridgeb;
  ip.inject = inject;
  inject_kernel<<<dim3(64, 2, 7), 256, 0, stream>>>(ip);

  GateParams gp;
  gp.bands = bands_bf; gp.inject = inject;
  gp.gatew = gatew_bf; gp.gateb = gateb;
  for (int i = 0; i < 7; ++i) gp.bandf[i] = band[i];
  gp.out = (float*)d_out;
  gate_kernel<<<dim3(64, 2, 7), 256, 0, stream>>>(gp);
}